// Round 6
// baseline (128.207 us; speedup 1.0000x reference)
//
#include <hip/hip_runtime.h>

#define T_SEQ 4096
#define NH    12

typedef _Float16 half8  __attribute__((ext_vector_type(8)));
typedef _Float16 half4  __attribute__((ext_vector_type(4)));
typedef float    floatx4 __attribute__((ext_vector_type(4)));

// Sliding-window attention, window [gq-128, gq+128) ∩ [0,T).
// r6: FATTER WAVES on the proven r5 skeleton. One WG = 128 query rows;
// 4 waves * 32 rows (2 subtiles of 16 each). Grid 768 = EXACTLY 3 WG/CU.
// LDS 32 KB (single-buffered K/V + 8 Ps slabs). Each kf/vf LDS read feeds
// TWO MFMAs (one per subtile); K/V staging + barriers per query ~halved
// (6 chunks per 128 queries vs 5 per 64). 12 waves/CU x 2 streams/wave
// ~= r5's 24-wave TLP.
// Kept verbatim from r5 (all harness-verified): swapped QK^T -> S^T with
// b64 P-writes, fused row-sum, v_exp_f32 with log2e folded into Q scale,
// setprio(1) around MFMA (T5), raw lgkmcnt-only barriers (T4: prefetch
// globals stay in flight), plane-grouped XCD map, single prefetch slot.
// Plain __launch_bounds__(256): min-waves forcing caused spills (r2-r4).
__global__ __launch_bounds__(256) void local_attn_f16(
    const float* __restrict__ Qg, const float* __restrict__ Kg,
    const float* __restrict__ Vg, float* __restrict__ Og)
{
    // XOR-swizzled 16B-block layouts: element (row,x) at
    // row*64 + (((x>>3) ^ (row&7))*8) + (x&7)   [halves]
    __shared__ _Float16 Ks[64 * 64];     // K chunk  [key][d]   (single buf)
    __shared__ _Float16 Vt[64 * 64];     // V^T      [d][key]   (single buf)
    __shared__ _Float16 Ps[8][16 * 64];  // per-(wave,subtile) P [qrow][key]

    const int t    = threadIdx.x;
    const int w    = t >> 6;        // wave id 0..3
    const int lane = t & 63;
    const int n    = lane & 15;     // MFMA 16-index (query col of S^T)
    const int qd   = lane >> 4;     // quad 0..3

    // Plane-grouped XCD map: wgid%8 == bx&7 (gridX=32). XCD j owns planes
    // 3j..3j+2; within an XCD, adjacent tiles are temporally adjacent.
    const int bx = blockIdx.x;                    // 0..31
    const int uu = blockIdx.y + NH * blockIdx.z;  // 0..23
    const int plane = 3 * (bx & 7) + (uu >> 3);   // 0..23
    const int tile  = (bx >> 3) + 4 * (uu & 7);   // 0..31
    const int s     = tile << 7;                  // query tile start (128 rows)
    const size_t planeoff = (size_t)plane * (size_t)(T_SEQ * 64);

    const float* Qp = Qg + planeoff;
    const float* Kp = Kg + planeoff;
    const float* Vp = Vg + planeoff;
    float*       Op = Og + planeoff;

    // staging thread mappings (64-key chunk staged by all 256 threads)
    const int kr0 = t >> 3;          // K rows 0..31
    const int kr1 = 32 + (t >> 3);   // K rows 32..63
    const int kbi = t & 7;           // 8-float block within row
    const int vd  = t & 63;          // V^T: this thread owns column d
    const int vjb = t >> 6;          // 16-key range per wave

    // ---- single prefetch slot (32 f32 regs, live across one compute) ----
    floatx4 kp0, kp1, kp2, kp3;
    float   vp[16];

    auto prefetchKV = [&](int c) {   // issue 20 loads, no wait
        const int gk0 = s - 128 + 64 * c;
        const float* kb = Kp + (size_t)gk0 * 64 + kbi * 8;
        kp0 = *(const floatx4*)(kb + (size_t)kr0 * 64);
        kp1 = *(const floatx4*)(kb + (size_t)kr0 * 64 + 4);
        kp2 = *(const floatx4*)(kb + (size_t)kr1 * 64);
        kp3 = *(const floatx4*)(kb + (size_t)kr1 * 64 + 4);
        const float* vb = Vp + (size_t)(gk0 + vjb * 16) * 64 + vd;
        #pragma unroll
        for (int j = 0; j < 16; ++j)         // coalesced 256B/wave each
            vp[j] = vb[(size_t)j * 64];
    };

    auto commitKV = [&]() {          // counted vmcnt waits, convert, ds_write
        half8 h0, h1, v0, v1;
        #pragma unroll
        for (int i = 0; i < 4; ++i) {
            h0[i] = (_Float16)kp0[i]; h0[i + 4] = (_Float16)kp1[i];
            h1[i] = (_Float16)kp2[i]; h1[i + 4] = (_Float16)kp3[i];
        }
        #pragma unroll
        for (int i = 0; i < 8; ++i) {
            v0[i] = (_Float16)vp[i];
            v1[i] = (_Float16)vp[8 + i];
        }
        *(half8*)&Ks[kr0 * 64 + (kbi ^ (kr0 & 7)) * 8] = h0;
        *(half8*)&Ks[kr1 * 64 + (kbi ^ (kr1 & 7)) * 8] = h1;
        *(half8*)&Vt[vd * 64 + ((2 * vjb)     ^ (vd & 7)) * 8] = v0;
        *(half8*)&Vt[vd * 64 + ((2 * vjb + 1) ^ (vd & 7)) * 8] = v1;
    };

    // valid chunk range: gk0 = s-128+64c in [0, T-64]; 128-row tile -> 6 chunks
    const int cbeg = (s == 0) ? 2 : 0;
    const int cend = (s == T_SEQ - 128) ? 3 : 5;

    // ---- prologue: chunk cbeg loads in flight while Q fragments build ----
    prefetchKV(cbeg);
    half8 qf[2][2];                  // [subtile u][ks]
    {
        const float qscale = 0.125f * 1.44269504088896340736f;  // /sqrt(64)*log2e
        #pragma unroll
        for (int u = 0; u < 2; ++u) {
            const float* qptr = Qp + (size_t)(s + 32 * w + 16 * u + n) * 64 + qd * 8;
            #pragma unroll
            for (int ks = 0; ks < 2; ++ks) {
                floatx4 a = *(const floatx4*)(qptr + 32 * ks);
                floatx4 b = *(const floatx4*)(qptr + 32 * ks + 4);
                half8 h;
                #pragma unroll
                for (int i = 0; i < 4; ++i) {
                    h[i]     = (_Float16)(a[i] * qscale);
                    h[i + 4] = (_Float16)(b[i] * qscale);
                }
                qf[u][ks] = h;
            }
        }
    }

    floatx4 Oacc[2][4] = {{{0.f,0.f,0.f,0.f},{0.f,0.f,0.f,0.f},
                           {0.f,0.f,0.f,0.f},{0.f,0.f,0.f,0.f}},
                          {{0.f,0.f,0.f,0.f},{0.f,0.f,0.f,0.f},
                           {0.f,0.f,0.f,0.f},{0.f,0.f,0.f,0.f}}};
    float Lsum[2] = {0.f, 0.f};

    // Raw barrier: publish LDS writes, do NOT drain vmcnt (T4).
    #define WG_BARRIER() do {                                        \
        __builtin_amdgcn_sched_barrier(0);                           \
        asm volatile("s_waitcnt lgkmcnt(0)" ::: "memory");           \
        __builtin_amdgcn_s_barrier();                                \
        __builtin_amdgcn_sched_barrier(0);                           \
    } while (0)

    auto compute = [&](int c) {
        const int c64 = 64 * c;
        const int wb0 = 32 * w;
        const int wb1 = 32 * w + 16;
        // subtile active iff some (key, query) pair in window:
        // valid(kk,q): 0 <= 64c + kk - qloc < 256
        const bool act0 = (c64 + 63 >= wb0) && (c64 < wb0 + 271);
        const bool act1 = (c64 + 63 >= wb1) && (c64 < wb1 + 271);
        if (!act0 && !act1) return;      // wave-uniform; barriers are outside

        // ---- S^T = K (Q*log2e)^T : 8 kf reads feed 16 MFMAs (2 subtiles) ----
        floatx4 acc[2][4] = {{{0.f,0.f,0.f,0.f},{0.f,0.f,0.f,0.f},
                              {0.f,0.f,0.f,0.f},{0.f,0.f,0.f,0.f}},
                             {{0.f,0.f,0.f,0.f},{0.f,0.f,0.f,0.f},
                              {0.f,0.f,0.f,0.f},{0.f,0.f,0.f,0.f}}};
        __builtin_amdgcn_s_setprio(1);
        #pragma unroll
        for (int ks = 0; ks < 2; ++ks) {
            #pragma unroll
            for (int tt = 0; tt < 4; ++tt) {
                const int key = tt * 16 + n;
                half8 kf = *(const half8*)&Ks[key * 64 + (((ks << 2) | qd) ^ (key & 7)) * 8];
                if (act0) acc[0][tt] = __builtin_amdgcn_mfma_f32_16x16x32_f16(kf, qf[0][ks], acc[0][tt], 0, 0, 0);
                if (act1) acc[1][tt] = __builtin_amdgcn_mfma_f32_16x16x32_f16(kf, qf[1][ks], acc[1][tt], 0, 0, 0);
            }
        }
        __builtin_amdgcn_s_setprio(0);

        // ---- masks + P = exp2(S') + fused row-sum + b64 P-writes, per u ----
        #pragma unroll
        for (int u = 0; u < 2; ++u) {
            if (!(u ? act1 : act0)) continue;
            const int wbase = 32 * w + 16 * u;
            const int qloc  = wbase + n;
            _Float16* PwU   = &Ps[2 * w + u][0];
            if (c64 < wbase + 16) {              // lower edge crosses subtile
                const int tLo = qloc - c64;      // kk <  tLo -> invalid
                #pragma unroll
                for (int tt = 0; tt < 4; ++tt)
                    #pragma unroll
                    for (int rg = 0; rg < 4; ++rg)
                        if (tt * 16 + qd * 4 + rg < tLo) acc[u][tt][rg] = -1e30f;
            }
            if (c64 >= wbase + 193) {            // upper edge crosses subtile
                const int tHi = qloc + 256 - c64; // kk >= tHi -> invalid
                #pragma unroll
                for (int tt = 0; tt < 4; ++tt)
                    #pragma unroll
                    for (int rg = 0; rg < 4; ++rg)
                        if (tt * 16 + qd * 4 + rg >= tHi) acc[u][tt][rg] = -1e30f;
            }
            #pragma unroll
            for (int tt = 0; tt < 4; ++tt) {
                float p0, p1, p2, p3;
                asm("v_exp_f32 %0, %1" : "=v"(p0) : "v"(acc[u][tt][0]));
                asm("v_exp_f32 %0, %1" : "=v"(p1) : "v"(acc[u][tt][1]));
                asm("v_exp_f32 %0, %1" : "=v"(p2) : "v"(acc[u][tt][2]));
                asm("v_exp_f32 %0, %1" : "=v"(p3) : "v"(acc[u][tt][3]));
                Lsum[u] += (p0 + p1) + (p2 + p3);
                half4 pk;
                pk[0] = (_Float16)p0; pk[1] = (_Float16)p1;
                pk[2] = (_Float16)p2; pk[3] = (_Float16)p3;
                // keys 16tt+4qd..+3, query n: contiguous 8B (block 2tt+(qd>>1))
                *(half4*)&PwU[n * 64 + ((2 * tt + (qd >> 1)) ^ (n & 7)) * 8 + (qd & 1) * 4] = pk;
            }
        }

        // Ps is per-wave: drain DS writes only, no WG barrier.
        asm volatile("s_waitcnt lgkmcnt(0)" ::: "memory");

        // ---- O += P V : 8 vf reads feed 16 MFMAs (2 subtiles) ----
        __builtin_amdgcn_s_setprio(1);
        #pragma unroll
        for (int js = 0; js < 2; ++js) {
            half8 pf0 = *(const half8*)&Ps[2 * w    ][n * 64 + (((js << 2) | qd) ^ (n & 7)) * 8];
            half8 pf1 = *(const half8*)&Ps[2 * w + 1][n * 64 + (((js << 2) | qd) ^ (n & 7)) * 8];
            #pragma unroll
            for (int tt = 0; tt < 4; ++tt) {
                const int d = tt * 16 + n;
                half8 vf = *(const half8*)&Vt[d * 64 + (((js << 2) | qd) ^ (d & 7)) * 8];
                if (act0) Oacc[0][tt] = __builtin_amdgcn_mfma_f32_16x16x32_f16(pf0, vf, Oacc[0][tt], 0, 0, 0);
                if (act1) Oacc[1][tt] = __builtin_amdgcn_mfma_f32_16x16x32_f16(pf1, vf, Oacc[1][tt], 0, 0, 0);
            }
        }
        __builtin_amdgcn_s_setprio(0);
    };

    // ---- prologue part 2: stage chunk cbeg, issue cbeg+1 (>=4 chunks) ----
    commitKV();                 // one exposed vmcnt wait per WG
    prefetchKV(cbeg + 1);
    WG_BARRIER();               // chunk cbeg visible; cbeg+1 loads in flight

    // ---- rolled main loop, single LDS buffer, 2 raw barriers/chunk ----
    #pragma unroll 1
    for (int c = cbeg; c <= cend; ++c) {
        compute(c);
        if (c < cend) {
            WG_BARRIER();                       // all waves done reading Ks/Vt
            commitKV();                         // chunk c+1 (loads in flight
                                                //  since before compute(c))
            if (c + 2 <= cend) prefetchKV(c + 2);
            WG_BARRIER();                       // chunk c+1 published
        }
    }

    // ---- epilogue: reduce l across quads, divide, store fp32 (per u) ----
    #pragma unroll
    for (int u = 0; u < 2; ++u) {
        float lt = Lsum[u] + __shfl_xor(Lsum[u], 16, 64);
        lt += __shfl_xor(lt, 32, 64);          // lanes sharing n: full L(query n)
        #pragma unroll
        for (int rg = 0; rg < 4; ++rg) {
            const float lr = __shfl(lt, qd * 4 + rg, 64);  // L for this row
            const float inv = 1.0f / lr;
            float* op = Op + (size_t)(s + 32 * w + 16 * u + qd * 4 + rg) * 64 + n;
            op[0]  = Oacc[u][0][rg] * inv;
            op[16] = Oacc[u][1][rg] * inv;
            op[32] = Oacc[u][2][rg] * inv;
            op[48] = Oacc[u][3][rg] * inv;
        }
    }
}

extern "C" void kernel_launch(void* const* d_in, const int* in_sizes, int n_in,
                              void* d_out, int out_size, void* d_ws, size_t ws_size,
                              hipStream_t stream) {
    const float* q = (const float*)d_in[0];
    const float* k = (const float*)d_in[1];
    const float* v = (const float*)d_in[2];
    float* o = (float*)d_out;
    dim3 grid(T_SEQ / 128, NH, 2);
    dim3 block(256);
    local_attn_f16<<<grid, block, 0, stream>>>(q, k, v, o);
}

// Round 7
// 119.925 us; speedup vs baseline: 1.0691x; 1.0691x over previous
//
#include <hip/hip_runtime.h>

#define T_SEQ 4096
#define NH    12

typedef _Float16 half8  __attribute__((ext_vector_type(8)));
typedef _Float16 half4  __attribute__((ext_vector_type(4)));
typedef float    floatx4 __attribute__((ext_vector_type(4)));

// Sliding-window attention, window [gq-128, gq+128) ∩ [0,T).
// r7 = r5 base (proven best: 4 waves/64 rows, single-buf, 6 WG/CU) with the
// P LDS ROUND-TRIP ELIMINATED via a key-permutation trick:
//   The key dim is summed in PV, so storing V^T with keys permuted by
//   pi(32js+8qd+j) = 32js+16(j>>2)+4qd+(j&3)  (bit perm, applied at staging)
//   makes the PV A-fragment equal the lane's OWN packed exp outputs:
//   pf[js] = concat(pk[2js], pk[2js+1]). Zero shuffles, zero P-writes,
//   zero P-reads, no mid-compute lgkmcnt drain. Ps array deleted: LDS 16 KB.
// Kept from r5 (harness-verified): swapped QK^T -> S^T, fused row-sum,
// v_exp_f32 with log2e folded into Q scale, setprio(1) around MFMA (T5),
// raw lgkmcnt-only barriers (T4: prefetch globals stay in flight), single
// prefetch slot, plane-grouped XCD map, plain __launch_bounds__(256)
// (min-waves forcing spilled in r2-r4). Grid 1536 = exactly 6 WG/CU.
__global__ __launch_bounds__(256) void local_attn_f16(
    const float* __restrict__ Qg, const float* __restrict__ Kg,
    const float* __restrict__ Vg, float* __restrict__ Og)
{
    // XOR-swizzled 16B-block layouts: element (row,x) at
    // row*64 + (((x>>3) ^ (row&7))*8) + (x&7)   [halves]
    __shared__ _Float16 Ks[64 * 64];     // K chunk  [key][d]       (single buf)
    __shared__ _Float16 Vt[64 * 64];     // V^T      [d][pi(key)]   (single buf)

    const int t    = threadIdx.x;
    const int w    = t >> 6;        // wave id 0..3
    const int lane = t & 63;
    const int n    = lane & 15;     // MFMA 16-index (query col of S^T)
    const int qd   = lane >> 4;     // quad 0..3

    // Plane-grouped XCD map: wgid%8 == bx&7 (gridX=64). XCD j owns planes
    // 3j..3j+2; within an XCD, adjacent tiles are temporally adjacent.
    const int bx = blockIdx.x;                    // 0..63
    const int uu = blockIdx.y + NH * blockIdx.z;  // 0..23
    const int plane = 3 * (bx & 7) + (uu >> 3);   // 0..23
    const int tile  = (bx >> 3) + 8 * (uu & 7);   // 0..63
    const int s     = tile << 6;                  // query tile start (64 rows)
    const size_t planeoff = (size_t)plane * (size_t)(T_SEQ * 64);

    const float* Qp = Qg + planeoff;
    const float* Kp = Kg + planeoff;
    const float* Vp = Vg + planeoff;
    float*       Op = Og + planeoff;

    // staging thread mappings (64-key chunk staged by all 256 threads)
    const int kr0 = t >> 3;          // K rows 0..31
    const int kr1 = 32 + (t >> 3);   // K rows 32..63
    const int kbi = t & 7;           // 8-float block within row
    const int vd  = t & 63;          // V^T: this thread owns column d
    const int vjb = t >> 6;          // 16-col (permuted) range per wave
    // permuted V key base: cols 16*vjb+m hold keys kbase+{0..7,16..23}
    const int kbase = 32 * (vjb >> 1) + 8 * (vjb & 1);

    // ---- single prefetch slot (32 f32 regs, live across one compute) ----
    floatx4 kp0, kp1, kp2, kp3;
    float   vp[16];

    auto prefetchKV = [&](int c) {   // issue 20 loads, no wait
        const int gk0 = s - 128 + 64 * c;
        const float* kb = Kp + (size_t)gk0 * 64 + kbi * 8;
        kp0 = *(const floatx4*)(kb + (size_t)kr0 * 64);
        kp1 = *(const floatx4*)(kb + (size_t)kr0 * 64 + 4);
        kp2 = *(const floatx4*)(kb + (size_t)kr1 * 64);
        kp3 = *(const floatx4*)(kb + (size_t)kr1 * 64 + 4);
        const float* vb = Vp + (size_t)(gk0 + kbase) * 64 + vd;
        #pragma unroll
        for (int j = 0; j < 16; ++j)         // coalesced 256B/wave each
            vp[j] = vb[(size_t)((j >> 3) * 16 + (j & 7)) * 64];  // keys kbase+0..7,16..23
    };

    auto commitKV = [&]() {          // counted vmcnt waits, convert, ds_write
        half8 h0, h1, v0, v1;
        #pragma unroll
        for (int i = 0; i < 4; ++i) {
            h0[i] = (_Float16)kp0[i]; h0[i + 4] = (_Float16)kp1[i];
            h1[i] = (_Float16)kp2[i]; h1[i + 4] = (_Float16)kp3[i];
        }
        // col m of this thread's 16-col range (c = 16*vjb+m) holds key
        // pi(c): m 0..3 -> loads 0..3, m 4..7 -> loads 8..11,
        //        m 8..11 -> loads 4..7, m 12..15 -> loads 12..15
        #pragma unroll
        for (int i = 0; i < 4; ++i) {
            v0[i]     = (_Float16)vp[i];        // m = 0..3
            v0[i + 4] = (_Float16)vp[8 + i];    // m = 4..7
            v1[i]     = (_Float16)vp[4 + i];    // m = 8..11
            v1[i + 4] = (_Float16)vp[12 + i];   // m = 12..15
        }
        *(half8*)&Ks[kr0 * 64 + (kbi ^ (kr0 & 7)) * 8] = h0;
        *(half8*)&Ks[kr1 * 64 + (kbi ^ (kr1 & 7)) * 8] = h1;
        *(half8*)&Vt[vd * 64 + ((2 * vjb)     ^ (vd & 7)) * 8] = v0;
        *(half8*)&Vt[vd * 64 + ((2 * vjb + 1) ^ (vd & 7)) * 8] = v1;
    };

    const int cbeg = (s == 0) ? 2 : (s == 64) ? 1 : 0;
    const int cend = (s == T_SEQ - 64) ? 2 : (s == T_SEQ - 128) ? 3 : 4;

    // ---- prologue: chunk cbeg loads in flight while Q fragments build ----
    prefetchKV(cbeg);
    half8 qf[2];
    {
        const float* qptr = Qp + (size_t)(s + 16 * w + n) * 64 + qd * 8;
        const float qscale = 0.125f * 1.44269504088896340736f;  // /sqrt(64)*log2e
        #pragma unroll
        for (int ks = 0; ks < 2; ++ks) {
            floatx4 a = *(const floatx4*)(qptr + 32 * ks);
            floatx4 b = *(const floatx4*)(qptr + 32 * ks + 4);
            half8 h;
            #pragma unroll
            for (int i = 0; i < 4; ++i) {
                h[i]     = (_Float16)(a[i] * qscale);
                h[i + 4] = (_Float16)(b[i] * qscale);
            }
            qf[ks] = h;
        }
    }

    floatx4 Oacc[4] = {{0.f,0.f,0.f,0.f},{0.f,0.f,0.f,0.f},
                       {0.f,0.f,0.f,0.f},{0.f,0.f,0.f,0.f}};
    float Lsum = 0.f;

    // Raw barrier: publish LDS writes, do NOT drain vmcnt (T4).
    #define WG_BARRIER() do {                                        \
        __builtin_amdgcn_sched_barrier(0);                           \
        asm volatile("s_waitcnt lgkmcnt(0)" ::: "memory");           \
        __builtin_amdgcn_s_barrier();                                \
        __builtin_amdgcn_sched_barrier(0);                           \
    } while (0)

    auto compute = [&](int c) {
        // ---- S^T = K (Q*log2e)^T : 8 MFMAs; S^T[key=16tt+4qd+rg][query=n] ----
        floatx4 acc[4] = {{0.f,0.f,0.f,0.f},{0.f,0.f,0.f,0.f},
                          {0.f,0.f,0.f,0.f},{0.f,0.f,0.f,0.f}};
        __builtin_amdgcn_s_setprio(1);
        #pragma unroll
        for (int ks = 0; ks < 2; ++ks) {
            #pragma unroll
            for (int tt = 0; tt < 4; ++tt) {
                const int key = tt * 16 + n;
                half8 kf = *(const half8*)&Ks[key * 64 + (((ks << 2) | qd) ^ (key & 7)) * 8];
                acc[tt] = __builtin_amdgcn_mfma_f32_16x16x32_f16(kf, qf[ks], acc[tt], 0, 0, 0);
            }
        }
        __builtin_amdgcn_s_setprio(0);

        // ---- window masks (key kk valid iff 0 <= 64c+kk-qloc < 256):
        // lower edge only at c==0 (kk < qloc), upper only at c==4 (kk >= qloc)
        const int qloc = 16 * w + n;
        if (c == 0) {
            #pragma unroll
            for (int tt = 0; tt < 4; ++tt)
                #pragma unroll
                for (int rg = 0; rg < 4; ++rg)
                    if (tt * 16 + qd * 4 + rg < qloc) acc[tt][rg] = -1e30f;
        } else if (c == 4) {
            #pragma unroll
            for (int tt = 0; tt < 4; ++tt)
                #pragma unroll
                for (int rg = 0; rg < 4; ++rg)
                    if (tt * 16 + qd * 4 + rg >= qloc) acc[tt][rg] = -1e30f;
        }

        // ---- P = exp2(S'), fused row-sum, pack IN REGISTERS ----
        // pf[js] slot j holds key pi(32js+8qd+j) = 16(2js+(j>>2))+4qd+(j&3)
        //  -> pf[js] = (p[2js][0..3], p[2js+1][0..3]): the lane's own values.
        half8 pf[2];
        #pragma unroll
        for (int tt = 0; tt < 4; ++tt) {
            float p0, p1, p2, p3;
            asm("v_exp_f32 %0, %1" : "=v"(p0) : "v"(acc[tt][0]));
            asm("v_exp_f32 %0, %1" : "=v"(p1) : "v"(acc[tt][1]));
            asm("v_exp_f32 %0, %1" : "=v"(p2) : "v"(acc[tt][2]));
            asm("v_exp_f32 %0, %1" : "=v"(p3) : "v"(acc[tt][3]));
            Lsum += (p0 + p1) + (p2 + p3);
            const int hi = (tt & 1) * 4;
            pf[tt >> 1][hi]     = (_Float16)p0;
            pf[tt >> 1][hi + 1] = (_Float16)p1;
            pf[tt >> 1][hi + 2] = (_Float16)p2;
            pf[tt >> 1][hi + 3] = (_Float16)p3;
        }

        // ---- O += P V  (pf in regs; Vt stores pi-permuted keys) ----
        __builtin_amdgcn_s_setprio(1);
        #pragma unroll
        for (int js = 0; js < 2; ++js) {
            #pragma unroll
            for (int tt = 0; tt < 4; ++tt) {
                const int d = tt * 16 + n;
                half8 vf = *(const half8*)&Vt[d * 64 + (((js << 2) | qd) ^ (d & 7)) * 8];
                Oacc[tt] = __builtin_amdgcn_mfma_f32_16x16x32_f16(pf[js], vf, Oacc[tt], 0, 0, 0);
            }
        }
        __builtin_amdgcn_s_setprio(0);
    };

    // ---- prologue part 2: stage chunk cbeg, issue cbeg+1 (>=3 chunks) ----
    commitKV();                 // one exposed vmcnt wait per WG
    prefetchKV(cbeg + 1);
    WG_BARRIER();               // chunk cbeg visible; cbeg+1 loads in flight

    // ---- rolled main loop, single LDS buffer, 2 raw barriers/chunk ----
    #pragma unroll 1
    for (int c = cbeg; c <= cend; ++c) {
        compute(c);
        if (c < cend) {
            WG_BARRIER();                       // all waves done reading Ks/Vt
            commitKV();                         // chunk c+1 (loads in flight
                                                //  since before compute(c))
            if (c + 2 <= cend) prefetchKV(c + 2);
            WG_BARRIER();                       // chunk c+1 published
        }
    }

    // ---- epilogue: reduce l across quads, divide, store fp32 ----
    float lt = Lsum + __shfl_xor(Lsum, 16, 64);
    lt += __shfl_xor(lt, 32, 64);              // lanes sharing n: full L(query n)
    #pragma unroll
    for (int rg = 0; rg < 4; ++rg) {
        const float lr = __shfl(lt, qd * 4 + rg, 64);  // L for this output row
        const float inv = 1.0f / lr;
        float* op = Op + (size_t)(s + 16 * w + qd * 4 + rg) * 64 + n;
        op[0]  = Oacc[0][rg] * inv;
        op[16] = Oacc[1][rg] * inv;
        op[32] = Oacc[2][rg] * inv;
        op[48] = Oacc[3][rg] * inv;
    }
}

extern "C" void kernel_launch(void* const* d_in, const int* in_sizes, int n_in,
                              void* d_out, int out_size, void* d_ws, size_t ws_size,
                              hipStream_t stream) {
    const float* q = (const float*)d_in[0];
    const float* k = (const float*)d_in[1];
    const float* v = (const float*)d_in[2];
    float* o = (float*)d_out;
    dim3 grid(T_SEQ / 64, NH, 2);
    dim3 block(256);
    local_attn_f16<<<grid, block, 0, stream>>>(q, k, v, o);
}